// Round 7
// baseline (1578.211 us; speedup 1.0000x reference)
//
#include <hip/hip_runtime.h>
#include <hip/hip_cooperative_groups.h>

// f32 in/out pipeline: MFMA split-bf16 GEMMs + CSR gathers.
// Round 15: cooperative mega-kernel, SAFE edition. R14's failure is consistent
// with the coop launch being rejected (512 blocks x 2/CU co-residency) with the
// error ignored. Now: 256 blocks x 1024 thr (1 block/CU, trivially co-resident),
// 144KB static LDS so gemm phases are R4's PROVEN whole-B/128-row-tile structure
// verbatim; gathers/scatter/build are R4/R13 bodies at stride 1024; explicit
// __threadfence() before each grid.sync(); and the launch return code is
// CHECKED - on any error we fall back to 11 standalone wrappers around the same
// __device__ phase functions (structurally == R4, 274us, passing).

namespace cg = cooperative_groups;

typedef unsigned short u16;
typedef unsigned int   u32;
typedef _Float16 f16;
typedef __attribute__((ext_vector_type(8))) short short8;     // 8 bf16 (4 VGPRs)
typedef __attribute__((ext_vector_type(8))) _Float16 half8;   // 8 f16 (16B)
typedef __attribute__((ext_vector_type(4))) float f32x4;      // MFMA C/D frag

static const int BCAP = 3072;   // tmp capacity per 128-id bucket (mean fill ~2046)

__device__ __forceinline__ float bf2f(u16 u) {
    return __builtin_bit_cast(float, (u32)u << 16);
}
__device__ __forceinline__ u16 f2bf(float f) {
    u32 b = __builtin_bit_cast(u32, f);
    b += 0x7FFFu + ((b >> 16) & 1u);   // RNE (finite)
    return (u16)(b >> 16);
}

__device__ __forceinline__ void wsplit_one(const float* __restrict__ W, u16* __restrict__ out,
                                           int K, int N, int local)
{
    int kp = local % 72;
    int rest = local / 72;
    int n = rest % N;
    int c = rest / N;
    float v = 0.f;
    if (kp < 64) v = W[(size_t)(c * 64 + kp) * N + n];
    u16 h = f2bf(v);
    u16 l = f2bf(v - bf2f(h));
    size_t base = (size_t)c * (2 * (size_t)N * 72);
    out[base + (size_t)n * 72 + kp] = h;
    out[base + (size_t)N * 72 + (size_t)n * 72 + kp] = l;
}

__device__ __forceinline__ void split8(const float* __restrict__ p, short8& hi, short8& lo) {
    #pragma unroll
    for (int j = 0; j < 8; ++j) {
        float v = p[j];
        u16 h = f2bf(v);
        hi[j] = (short)h;
        lo[j] = (short)f2bf(v - bf2f(h));
    }
}

// ================= device phase functions (shared by mega + fallback) =================

// ---- weight split + cursor zero ----
__device__ __forceinline__ void phase_wsplit(
    const float* W1, const float* W2, const float* Wp,
    u16* w1sp, u16* w2sp, u16* wpsp, int* cursors,
    int tid, int bid, int NB)
{
    if (bid == 0) cursors[tid] = 0;        // 1024 ints: covers curEb + curNb
    const int T1 = 4 * 128 * 72, T2 = 2 * 64 * 72, T3 = 1 * 64 * 72;
    for (int idx = bid * 1024 + tid; idx < T1 + T2 + T3; idx += NB * 1024) {
        if (idx < T1)            wsplit_one(W1, w1sp, 256, 128, idx);
        else if (idx < T1 + T2)  wsplit_one(W2, w2sp, 128, 64, idx - T1);
        else                     wsplit_one(Wp, wpsp, 64, 64, idx - T1 - T2);
    }
}

// ---- Pass A: bin entries into fixed-capacity bucket regions ----
__device__ __forceinline__ void phase_scatter(
    const int* __restrict__ hidx, int* curEb, int* curNb,
    u32* __restrict__ tmpE, u32* __restrict__ tmpN,
    int nnz, int nNodes, int nEdges, char* smem, int tid, int bid, int NB)
{
    int* histE = (int*)smem;
    int* histN = histE + 400;
    int* s_st  = histN + 400;
    const int nbE = (nEdges + 127) >> 7, nbN = (nNodes + 127) >> 7;
    if (tid < 64) {
        unsigned long long mb = __ballot(hidx[2 * tid + 1] != 0);
        if (tid == 0) *s_st = (mb == 0ull) ? 2 : 1;   // all-zero odd words -> int64
    }
    __syncthreads();
    const int st = *s_st;
    const size_t eoff = (size_t)nnz * st;
    const int nchunk = (nnz + 4095) / 4096;
    for (int vw = bid; vw < nchunk; vw += NB) {
        for (int b = tid; b < 400; b += 1024) { histE[b] = 0; histN[b] = 0; }
        __syncthreads();
        int e_[4], n_[4], rE[4], rN[4];
        const int i0 = vw * 4096;
        #pragma unroll
        for (int k = 0; k < 4; ++k) {
            int i = i0 + k * 1024 + tid;
            int n = -1, e = 0;
            if (i < nnz) {
                n = hidx[(size_t)i * st];
                e = hidx[eoff + (size_t)i * st];
                if (!((u32)n < (u32)nNodes && (u32)e < (u32)nEdges)) n = -1;
            }
            n_[k] = n; e_[k] = e;
            if (n >= 0) {
                rE[k] = atomicAdd(&histE[e >> 7], 1);
                rN[k] = atomicAdd(&histN[n >> 7], 1);
            }
        }
        __syncthreads();
        for (int b = tid; b < nbE; b += 1024) { int c = histE[b]; if (c) histE[b] = atomicAdd(&curEb[b], c); }
        for (int b = tid; b < nbN; b += 1024) { int c = histN[b]; if (c) histN[b] = atomicAdd(&curNb[b], c); }
        __syncthreads();
        #pragma unroll
        for (int k = 0; k < 4; ++k) {
            if (n_[k] >= 0) {
                int e = e_[k], n = n_[k];
                int lpE = histE[e >> 7] + rE[k];
                int lpN = histN[n >> 7] + rN[k];
                if (lpE < BCAP) tmpE[(size_t)(e >> 7) * BCAP + lpE] = ((u32)(e & 127) << 16) | (u32)n;
                if (lpN < BCAP) tmpN[(size_t)(n >> 7) * BCAP + lpN] = ((u32)(n & 127) << 16) | (u32)e;
            }
        }
        __syncthreads();
    }
}

// ---- bucket-count scan -> CSR bases (virtual blocks 0/1, wave 0) ----
__device__ __forceinline__ void phase_scan(
    const int* curEb, const int* curNb, int* baseE, int* baseN,
    int nEdges, int nNodes, int tid, int bid)
{
    if (bid < 2 && tid < 64) {
        const int* cur = (bid == 0) ? curEb : curNb;
        int* base      = (bid == 0) ? baseE : baseN;
        const int nb   = (bid == 0) ? ((nEdges + 127) >> 7) : ((nNodes + 127) >> 7);
        int carry = 0;
        for (int c0 = 0; c0 < nb; c0 += 64) {
            int i = c0 + tid;
            int v = (i < nb) ? cur[i] : 0;
            int orig = v;
            for (int o = 1; o < 64; o <<= 1) { int u = __shfl_up(v, o, 64); if (tid >= o) v += u; }
            if (i < nb) base[i] = carry + v - orig;   // exclusive
            carry += __shfl(v, 63, 64);
        }
        if (tid == 0) base[nb] = carry;
    }
}

// ---- Pass B: per-bucket deg/offs/inv + CSR-ordered adj ----
__device__ __forceinline__ void phase_build(
    const u32* __restrict__ tmpE, const u32* __restrict__ tmpN,
    const int* __restrict__ baseE, const int* __restrict__ baseN,
    int* deg_e, int* offs_e, float* binv, u16* adj_e,
    int* deg_n, int* offs_n, float* dinv, u16* adj_n,
    int nE, int nN, char* smem, int tid, int bid, int NB)
{
    u32* buf  = (u32*)smem;                 // 4096 u32 = 16KB
    int* lcnt = (int*)(smem + 16384);
    int* lpre = lcnt + 128;
    int* lcur = lpre + 128;
    const int nbE = (nE + 127) >> 7, nbN = (nN + 127) >> 7;
    const int totalB = nbE + nbN;
    for (int vb = bid; vb < totalB; vb += NB) {
        const u32* tmp; const int* base; int* deg; int* offs; float* inv; u16* adj; int n, tb;
        if (vb < nbE) { tmp=tmpE; base=baseE; deg=deg_e; offs=offs_e; inv=binv; adj=adj_e; n=nE; tb=vb; }
        else          { tmp=tmpN; base=baseN; deg=deg_n; offs=offs_n; inv=dinv; adj=adj_n; n=nN; tb=vb-nbE; }
        const int g0 = tb << 7;
        const int gbase = base[tb];
        const int cnt = base[tb + 1] - gbase;
        const int avail = cnt < BCAP ? cnt : BCAP;
        const size_t tbase = (size_t)tb * BCAP;
        if (tid < 128) lcnt[tid] = 0;
        __syncthreads();
        for (int j = tid; j < avail; j += 1024) atomicAdd(&lcnt[tmp[tbase + j] >> 16], 1);
        __syncthreads();
        if (tid < 64) {
            int a0 = lcnt[2 * tid], a1 = lcnt[2 * tid + 1];
            int ps = a0 + a1, v = ps;
            for (int o = 1; o < 64; o <<= 1) { int u = __shfl_up(v, o, 64); if (tid >= o) v += u; }
            int excl = v - ps;
            lpre[2 * tid] = excl; lpre[2 * tid + 1] = excl + a0;
        }
        __syncthreads();
        if (tid < 128) {
            int id = g0 + tid;
            if (id < n) {
                int d = lcnt[tid];
                deg[id]  = d;
                offs[id] = gbase + lpre[tid];
                inv[id]  = d > 0 ? 1.0f / (float)d : 0.0f;
            }
            lcur[tid] = lpre[tid];
        }
        __syncthreads();
        for (int j = tid; j < avail; j += 1024) {
            u32 v = tmp[tbase + j];
            int pos = atomicAdd(&lcur[v >> 16], 1);
            buf[pos] = v & 0xFFFFu;
        }
        __syncthreads();
        for (int j = tid; j < avail; j += 1024) adj[gbase + j] = (u16)buf[j];
        __syncthreads();
    }
}

// ---- GEMM: R4's proven structure (whole pre-split B in LDS, 128-row tiles) ----
// C[M,N] = A[M,K] @ B[K,N] (+bias). A f32; B pre-split [K/64][2][N][72] bf16.
// 1024 thr = 16 waves: 8 row-groups x 2 N-halves. OUT: 0 f32 row-major,
// 1 f16 plane-major SW=32 (plane = col>>5). Requires M % 16 == 0.
template<int K, int N, bool BIAS, int OUT>
__device__ __forceinline__ void gemm_phase(
    const float* __restrict__ A, const u16* __restrict__ Bsp,
    const float* __restrict__ bias, void* __restrict__ C_,
    int M, char* smem, int tid, int bid, int NB)
{
    constexpr int KP = 72;
    constexpr int NCH = K / 64;
    constexpr int CHUNK = 2 * N * KP;              // u16 per 64-k chunk (hi+lo)
    constexpr int NTW = N / 32;
    u16* Bbuf = (u16*)smem;
    __syncthreads();                               // smem handoff from prior phase
    for (int u = tid; u < NCH * CHUNK / 8; u += 1024)
        *(float4*)(&Bbuf[(size_t)u * 8]) = *(const float4*)(Bsp + (size_t)u * 8);
    __syncthreads();
    const int wave = tid >> 6, lane = tid & 63;
    const int mg = wave >> 1, nh = wave & 1;
    const int lr = lane & 15, kq = (lane >> 4) * 8;
    const int nt0 = nh * NTW;
    const int MT = (M + 127) >> 7;
    for (int tile = bid; tile < MT; tile += NB) {
        const int row0 = tile * 128 + mg * 16;
        if (row0 >= M) continue;                   // no barriers in loop -> safe
        f32x4 acc[NTW];
        #pragma unroll
        for (int i = 0; i < NTW; ++i) acc[i] = (f32x4){0.f, 0.f, 0.f, 0.f};
        const float* Ap = A + (size_t)(row0 + lr) * K + kq;
        #pragma unroll
        for (int c = 0; c < NCH; ++c) {
            #pragma unroll
            for (int k0 = 0; k0 < 64; k0 += 32) {
                short8 ah, al;
                split8(Ap + c * 64 + k0, ah, al);
                #pragma unroll
                for (int f = 0; f < NTW; ++f) {
                    const int col = (nt0 + f) * 16 + lr;
                    const int bo = c * CHUNK + col * KP + k0 + kq;
                    const short8 bh = *(const short8*)(&Bbuf[bo]);
                    const short8 bl = *(const short8*)(&Bbuf[bo + N * KP]);
                    acc[f] = __builtin_amdgcn_mfma_f32_16x16x32_bf16(ah, bh, acc[f], 0, 0, 0);
                    acc[f] = __builtin_amdgcn_mfma_f32_16x16x32_bf16(al, bh, acc[f], 0, 0, 0);
                    acc[f] = __builtin_amdgcn_mfma_f32_16x16x32_bf16(ah, bl, acc[f], 0, 0, 0);
                }
            }
        }
        const int orow = row0 + (lane >> 4) * 4;
        #pragma unroll
        for (int f = 0; f < NTW; ++f) {
            const int col = (nt0 + f) * 16 + lr;
            float bv = 0.0f;
            if constexpr (BIAS) bv = bias[col];
            #pragma unroll
            for (int j = 0; j < 4; ++j) {
                float vv = acc[f][j] + bv;
                if constexpr (OUT == 0) {
                    ((float*)C_)[(size_t)(orow + j) * N + col] = vv;
                } else {                           // f16 planes of 32 channels
                    ((f16*)C_)[((size_t)(col >> 5) * M + (orow + j)) * 32 + (col & 31)] = (f16)vv;
                }
            }
        }
    }
}

// ---- gather: R4's XCD-sliced SW=32 planes; 256 rows per virtual block ----
template<int NP, bool FINAL, int C>
__device__ __forceinline__ void gather_phase(
    const f16* __restrict__ src, const u16* __restrict__ adj,
    const int* __restrict__ offs, const int* __restrict__ deg,
    const float* __restrict__ inv, const float* __restrict__ bias,
    void* __restrict__ dstv, int nRows, int nSrcRows, int tid, int bid, int NB)
{
    constexpr int SW = 32;                  // 64B rows: one fully-used line per access
    const int nchunk = (nRows + 255) >> 8;  // 256 rows per virtual block (TPR=4)
    const int total = nchunk * NP;
    const int sub = tid & 3;
    for (int vw = bid; vw < total; vw += NB) {     // NB%NP==0 -> plane constant per block
        const int plane = vw & (NP - 1);
        const int chunk = vw / NP;
        const int r = chunk * 256 + (tid >> 2);
        if (r >= nRows) continue;
        const f16* sp = src + (size_t)plane * nSrcRows * SW + sub * 8;
        int j = offs[r], e = j + deg[r];
        float a0[8], a1[8], a2[8], a3[8];
        #pragma unroll
        for (int q = 0; q < 8; ++q) { a0[q]=0.f; a1[q]=0.f; a2[q]=0.f; a3[q]=0.f; }
        for (; j + 4 <= e; j += 4) {
            int s0 = adj[j], s1 = adj[j+1], s2 = adj[j+2], s3 = adj[j+3];
            const half8 v0 = *(const half8*)(sp + (size_t)s0 * SW);
            const half8 v1 = *(const half8*)(sp + (size_t)s1 * SW);
            const half8 v2 = *(const half8*)(sp + (size_t)s2 * SW);
            const half8 v3 = *(const half8*)(sp + (size_t)s3 * SW);
            #pragma unroll
            for (int q = 0; q < 8; ++q) {
                a0[q] += (float)v0[q]; a1[q] += (float)v1[q];
                a2[q] += (float)v2[q]; a3[q] += (float)v3[q];
            }
        }
        for (; j < e; ++j) {
            int s0 = adj[j];
            const half8 v0 = *(const half8*)(sp + (size_t)s0 * SW);
            #pragma unroll
            for (int q = 0; q < 8; ++q) a0[q] += (float)v0[q];
        }
        float scv = inv[r];
        float rr[8];
        #pragma unroll
        for (int q = 0; q < 8; ++q) rr[q] = ((a0[q] + a1[q]) + (a2[q] + a3[q])) * scv;
        if constexpr (FINAL) {
            float* dst = (float*)dstv;
            size_t o = (size_t)r * C + plane * SW + sub * 8;
            const float* bp = bias + plane * SW + sub * 8;
            const float4 b0 = *(const float4*)(bp);
            const float4 b1 = *(const float4*)(bp + 4);
            float4 o0, o1;
            o0.x = fmaxf(rr[0] + b0.x, 0.0f); o0.y = fmaxf(rr[1] + b0.y, 0.0f);
            o0.z = fmaxf(rr[2] + b0.z, 0.0f); o0.w = fmaxf(rr[3] + b0.w, 0.0f);
            o1.x = fmaxf(rr[4] + b1.x, 0.0f); o1.y = fmaxf(rr[5] + b1.y, 0.0f);
            o1.z = fmaxf(rr[6] + b1.z, 0.0f); o1.w = fmaxf(rr[7] + b1.w, 0.0f);
            *(float4*)(dst + o)     = o0;
            *(float4*)(dst + o + 4) = o1;
        } else {
            f16* dst = (f16*)dstv;
            half8 ov;
            #pragma unroll
            for (int q = 0; q < 8; ++q) ov[q] = (f16)rr[q];
            *(half8*)(dst + ((size_t)plane * nRows + r) * SW + sub * 8) = ov;
        }
    }
}

// ================= params =================
struct Params {
    const float* x; const int* hidx;
    const float* W1; const float* b1; const float* W2; const float* b2;
    const float* Wp; const float* bp;
    float* z; float* f1; float* f2;
    int nnz, nNodes, nEdges;
    int *deg_e, *deg_n, *offs_e, *offs_n;
    float *binv, *dinv;
    int *curEb, *curNb, *baseE, *baseN;
    u16 *adj_e, *adj_n;
    f16 *h0, *m1, *h1w, *m2;
    u32 *tmpE, *tmpN;
    u16 *w1sp, *w2sp, *wpsp;
};

// ================= the mega kernel (256 blocks x 1024 thr, 1 block/CU) =================
__global__ __launch_bounds__(1024, 4) void hgnn_mega(Params P)
{
    __shared__ alignas(16) char smem[147456];      // 144KB: whole w1sp image
    cg::grid_group grid = cg::this_grid();
    const int tid = threadIdx.x;
    const int bid = blockIdx.x;
    const int NB  = gridDim.x;

    phase_wsplit(P.W1, P.W2, P.Wp, P.w1sp, P.w2sp, P.wpsp, P.curEb, tid, bid, NB);
    __threadfence(); grid.sync();
    phase_scatter(P.hidx, P.curEb, P.curNb, P.tmpE, P.tmpN, P.nnz, P.nNodes, P.nEdges,
                  smem, tid, bid, NB);
    __threadfence(); grid.sync();
    phase_scan(P.curEb, P.curNb, P.baseE, P.baseN, P.nEdges, P.nNodes, tid, bid);
    __threadfence(); grid.sync();
    phase_build(P.tmpE, P.tmpN, P.baseE, P.baseN,
                P.deg_e, P.offs_e, P.binv, P.adj_e,
                P.deg_n, P.offs_n, P.dinv, P.adj_n,
                P.nEdges, P.nNodes, smem, tid, bid, NB);
    __threadfence(); grid.sync();
    gemm_phase<256, 128, false, 1>(P.x, P.w1sp, nullptr, P.h0, P.nNodes, smem, tid, bid, NB);
    __threadfence(); grid.sync();
    gather_phase<4, false, 128>(P.h0, P.adj_e, P.offs_e, P.deg_e, P.binv, nullptr,
                                P.m1, P.nEdges, P.nNodes, tid, bid, NB);
    __threadfence(); grid.sync();
    gather_phase<4, true, 128>(P.m1, P.adj_n, P.offs_n, P.deg_n, P.dinv, P.b1,
                               P.f1, P.nNodes, P.nEdges, tid, bid, NB);
    __threadfence(); grid.sync();
    gemm_phase<128, 64, false, 1>(P.f1, P.w2sp, nullptr, P.h1w, P.nNodes, smem, tid, bid, NB);
    __threadfence(); grid.sync();
    gather_phase<2, false, 64>(P.h1w, P.adj_e, P.offs_e, P.deg_e, P.binv, nullptr,
                               P.m2, P.nEdges, P.nNodes, tid, bid, NB);
    __threadfence(); grid.sync();
    gather_phase<2, true, 64>(P.m2, P.adj_n, P.offs_n, P.deg_n, P.dinv, P.b2,
                              P.f2, P.nNodes, P.nEdges, tid, bid, NB);
    __threadfence(); grid.sync();
    gemm_phase<64, 64, true, 0>(P.f2, P.wpsp, P.bp, P.z, P.nNodes, smem, tid, bid, NB);
}

// ================= standalone fallback wrappers (== R4 pipeline) =================
__global__ __launch_bounds__(1024) void k_wsplit(Params P) {
    phase_wsplit(P.W1, P.W2, P.Wp, P.w1sp, P.w2sp, P.wpsp, P.curEb,
                 threadIdx.x, blockIdx.x, gridDim.x);
}
__global__ __launch_bounds__(1024) void k_scatter(Params P) {
    __shared__ alignas(16) char smem[3328];
    phase_scatter(P.hidx, P.curEb, P.curNb, P.tmpE, P.tmpN, P.nnz, P.nNodes, P.nEdges,
                  smem, threadIdx.x, blockIdx.x, gridDim.x);
}
__global__ __launch_bounds__(1024) void k_scan(Params P) {
    phase_scan(P.curEb, P.curNb, P.baseE, P.baseN, P.nEdges, P.nNodes,
               threadIdx.x, blockIdx.x);
}
__global__ __launch_bounds__(1024) void k_build(Params P) {
    __shared__ alignas(16) char smem[17920];
    phase_build(P.tmpE, P.tmpN, P.baseE, P.baseN,
                P.deg_e, P.offs_e, P.binv, P.adj_e,
                P.deg_n, P.offs_n, P.dinv, P.adj_n,
                P.nEdges, P.nNodes, smem, threadIdx.x, blockIdx.x, gridDim.x);
}
template<int K, int N, bool BIAS, int OUT>
__global__ __launch_bounds__(1024) void k_gemm(const float* A, const u16* B,
                                               const float* bias, void* C_, int M) {
    __shared__ alignas(16) u16 Bb[(K / 64) * 2 * N * 72];
    gemm_phase<K, N, BIAS, OUT>(A, B, bias, C_, M, (char*)Bb,
                                threadIdx.x, blockIdx.x, gridDim.x);
}
template<int NP, bool FINAL, int C>
__global__ __launch_bounds__(1024) void k_gather(const f16* src, const u16* adj,
    const int* offs, const int* deg, const float* inv, const float* bias,
    void* dst, int nRows, int nSrcRows) {
    gather_phase<NP, FINAL, C>(src, adj, offs, deg, inv, bias, dst, nRows, nSrcRows,
                               threadIdx.x, blockIdx.x, gridDim.x);
}

// ================= launcher =================
extern "C" void kernel_launch(void* const* d_in, const int* in_sizes, int n_in,
                              void* d_out, int out_size, void* d_ws, size_t ws_size,
                              hipStream_t stream)
{
    (void)n_in; (void)out_size; (void)ws_size;
    const int nnz    = in_sizes[1] / 2;    // 800000
    const int nNodes = in_sizes[0] / 256;  // 50000
    const int nEdges = 50000;              // N_EDGES (not derivable from inputs)

    char* w = (char*)d_ws;
    const size_t SEG = 200192;             // >= 50048*4, 256B aligned
    Params P;
    P.x = (const float*)d_in[0]; P.hidx = (const int*)d_in[1];
    P.W1 = (const float*)d_in[2]; P.b1 = (const float*)d_in[3];
    P.W2 = (const float*)d_in[4]; P.b2 = (const float*)d_in[5];
    P.Wp = (const float*)d_in[6]; P.bp = (const float*)d_in[7];
    P.z  = (float*)d_out;
    P.f1 = (float*)d_out + (size_t)nNodes * 64;
    P.f2 = (float*)d_out + (size_t)nNodes * 64 + (size_t)nNodes * 128;
    P.nnz = nnz; P.nNodes = nNodes; P.nEdges = nEdges;
    P.deg_e  = (int*)(w + 0 * SEG);
    P.deg_n  = (int*)(w + 1 * SEG);
    P.offs_e = (int*)(w + 2 * SEG);
    P.offs_n = (int*)(w + 3 * SEG);
    P.binv   = (float*)(w + 4 * SEG);
    P.dinv   = (float*)(w + 5 * SEG);
    P.curEb  = (int*)(w + 6 * SEG + 256);         // 1024 ints zeroed by phase_wsplit
    P.curNb  = (int*)(w + 6 * SEG + 2304);
    P.baseE  = (int*)(w + 6 * SEG + 4352);
    P.baseN  = (int*)(w + 6 * SEG + 6400);
    char* p = w + 6 * SEG + 8448;
    P.adj_e = (u16*)p;  p += (size_t)nnz * 2;
    P.adj_n = (u16*)p;  p += (size_t)nnz * 2;
    P.h0  = (f16*)p;                                        // 4 planes x N x 32
    P.m1  = (f16*)(p + (size_t)nNodes * 128 * 2);           // 4 planes x E x 32
    P.h1w = P.h0;                                           // 2 planes x N x 32 (reuse)
    P.m2  = (f16*)((char*)P.h0 + (size_t)nNodes * 64 * 2);  // disjoint from h1w
    P.w1sp = (u16*)(p + 2 * (size_t)nNodes * 128 * 2);
    P.w2sp = P.w1sp + 4 * 18432;
    P.wpsp = P.w2sp + 2 * 9216;
    const int nbE = (nEdges + 127) >> 7;
    P.tmpE = (u32*)P.m1;                                    // aliases m1 (dead until gather1)
    P.tmpN = P.tmpE + (size_t)nbE * BCAP;

    void* args[] = { (void*)&P };
    hipError_t err = hipLaunchCooperativeKernel((const void*)hgnn_mega,
                                                dim3(256), dim3(1024), args, 0, stream);
    if (err != hipSuccess) {
        (void)hipGetLastError();                            // clear sticky error
        // fallback: R4-equivalent 11-dispatch pipeline (same phase functions)
        k_wsplit<<<50, 1024, 0, stream>>>(P);
        k_scatter<<<(nnz + 4095) / 4096, 1024, 0, stream>>>(P);
        k_scan<<<2, 1024, 0, stream>>>(P);
        k_build<<<782, 1024, 0, stream>>>(P);
        k_gemm<256, 128, false, 1><<<256, 1024, 0, stream>>>(P.x, P.w1sp, nullptr, P.h0, nNodes);
        k_gather<4, false, 128><<<((nEdges + 255) / 256) * 4, 1024, 0, stream>>>(
            P.h0, P.adj_e, P.offs_e, P.deg_e, P.binv, nullptr, P.m1, nEdges, nNodes);
        k_gather<4, true, 128><<<((nNodes + 255) / 256) * 4, 1024, 0, stream>>>(
            P.m1, P.adj_n, P.offs_n, P.deg_n, P.dinv, P.b1, P.f1, nNodes, nEdges);
        k_gemm<128, 64, false, 1><<<391, 1024, 0, stream>>>(P.f1, P.w2sp, nullptr, P.h1w, nNodes);
        k_gather<2, false, 64><<<((nEdges + 255) / 256) * 2, 1024, 0, stream>>>(
            P.h1w, P.adj_e, P.offs_e, P.deg_e, P.binv, nullptr, P.m2, nEdges, nNodes);
        k_gather<2, true, 64><<<((nNodes + 255) / 256) * 2, 1024, 0, stream>>>(
            P.m2, P.adj_n, P.offs_n, P.deg_n, P.dinv, P.b2, P.f2, nNodes, nEdges);
        k_gemm<64, 64, true, 0><<<391, 1024, 0, stream>>>(P.f2, P.wpsp, P.bp, P.z, nNodes);
    }
}

// Round 8
// 264.970 us; speedup vs baseline: 5.9562x; 5.9562x over previous
//
#include <hip/hip_runtime.h>

// f32 in/out pipeline: MFMA split-bf16 GEMMs + CSR gathers.
// Round 16: cooperative fusion (R14/R15) abandoned - coop launch forces
// coherence-safe (uncached) global traffic: mega ran at 1491us with ALL pipes
// idle. Back to the proven R12 multi-dispatch structure (274us) with:
// (a) 12 -> 10 dispatches: cursor-zero folded into wsplit (R13-proven), bucket
//     scan folded into gemm1 launch (blocks 0-1, before their GEMM work);
// (b) gathers unrolled to 8 independent line-loads in flight (L2-latency-bound,
//     deg~16 -> 2 main-loop iterations, ~2x MLP);
// (c) scatter = R13's 1024-thread version (4x occupancy of R12's).
// SW=32 XCD-sliced f16 planes + persistent LDS-resident GEMMs unchanged.

typedef unsigned short u16;
typedef unsigned int   u32;
typedef _Float16 f16;
typedef __attribute__((ext_vector_type(8))) short short8;     // 8 bf16 (4 VGPRs)
typedef __attribute__((ext_vector_type(8))) _Float16 half8;   // 8 f16 (16B)
typedef __attribute__((ext_vector_type(4))) float f32x4;      // MFMA C/D frag

static const int BCAP = 3072;   // tmp capacity per 128-id bucket (mean fill ~2046)

__device__ __forceinline__ float bf2f(u16 u) {
    return __builtin_bit_cast(float, (u32)u << 16);
}
__device__ __forceinline__ u16 f2bf(float f) {
    u32 b = __builtin_bit_cast(u32, f);
    b += 0x7FFFu + ((b >> 16) & 1u);   // RNE (finite)
    return (u16)(b >> 16);
}

// ---------- one-time weight split: W[K,N] f32 -> [K/64][2][N][72] bf16 hi/lo ----------
__device__ __forceinline__ void wsplit_one(const float* __restrict__ W, u16* __restrict__ out,
                                           int K, int N, int local)
{
    int kp = local % 72;
    int rest = local / 72;
    int n = rest % N;
    int c = rest / N;
    float v = 0.f;
    if (kp < 64) v = W[(size_t)(c * 64 + kp) * N + n];
    u16 h = f2bf(v);
    u16 l = f2bf(v - bf2f(h));
    size_t base = (size_t)c * (2 * (size_t)N * 72);
    out[base + (size_t)n * 72 + kp] = h;
    out[base + (size_t)N * 72 + (size_t)n * 72 + kp] = l;
}

__global__ __launch_bounds__(256) void wsplit_all_kernel(
    const float* __restrict__ W1, const float* __restrict__ W2, const float* __restrict__ Wp,
    u16* __restrict__ w1sp, u16* __restrict__ w2sp, u16* __restrict__ wpsp,
    int* __restrict__ cursors)
{
    const int T1 = 4 * 128 * 72;   // 36864
    const int T2 = 2 * 64 * 72;    // 9216
    const int T3 = 1 * 64 * 72;    // 4608
    if (blockIdx.x == 0) {         // zero bucket cursors (4KB) - replaces memset launch
        for (int z = threadIdx.x; z < 1024; z += 256) cursors[z] = 0;
    }
    int idx = blockIdx.x * 256 + threadIdx.x;
    if (idx < T1)                 wsplit_one(W1, w1sp, 256, 128, idx);
    else if (idx < T1 + T2)       wsplit_one(W2, w2sp, 128, 64, idx - T1);
    else if (idx < T1 + T2 + T3)  wsplit_one(Wp, wpsp, 64, 64, idx - T1 - T2);
}

// ---------- Pass A: bin entries into fixed-capacity bucket regions ----------
// Bucket = id >> 7. Temp entry: ((id&127)<<16) | value (ids < 65536).
// 1024 threads/block (16 waves) for latency hiding.
__global__ __launch_bounds__(1024) void bin_scatter_kernel(
    const int* __restrict__ hidx,
    int* __restrict__ curEb, int* __restrict__ curNb,
    u32* __restrict__ tmpE, u32* __restrict__ tmpN,
    int nnz, int nNodes, int nEdges)
{
    __shared__ int histE[400], histN[400];
    __shared__ int s_st;
    int t = threadIdx.x;
    const int nbE = (nEdges + 127) >> 7, nbN = (nNodes + 127) >> 7;
    for (int b = t; b < 400; b += 1024) { histE[b] = 0; histN[b] = 0; }
    if (t < 64) {
        unsigned long long m = __ballot(hidx[2 * t + 1] != 0);
        if (t == 0) s_st = (m == 0ull) ? 2 : 1;   // all-zero odd words -> int64 layout
    }
    __syncthreads();
    int st = s_st;
    size_t eoff = (size_t)nnz * st;
    int i0 = blockIdx.x * 4096;
    int e_[4], n_[4]; int rE[4], rN[4];
    #pragma unroll
    for (int k = 0; k < 4; ++k) {
        int i = i0 + k * 1024 + t;
        int n = -1, e = 0;
        if (i < nnz) {
            n = hidx[(size_t)i * st];
            e = hidx[eoff + (size_t)i * st];
            if (!((u32)n < (u32)nNodes && (u32)e < (u32)nEdges)) n = -1;
        }
        n_[k] = n; e_[k] = e;
        if (n >= 0) {
            rE[k] = atomicAdd(&histE[e >> 7], 1);
            rN[k] = atomicAdd(&histN[n >> 7], 1);
        }
    }
    __syncthreads();
    for (int b = t; b < nbE; b += 1024) { int c = histE[b]; if (c) histE[b] = atomicAdd(&curEb[b], c); }
    for (int b = t; b < nbN; b += 1024) { int c = histN[b]; if (c) histN[b] = atomicAdd(&curNb[b], c); }
    __syncthreads();
    #pragma unroll
    for (int k = 0; k < 4; ++k) {
        if (n_[k] >= 0) {
            int e = e_[k], n = n_[k];
            int lpE = histE[e >> 7] + rE[k];
            int lpN = histN[n >> 7] + rN[k];
            if (lpE < BCAP) tmpE[(size_t)(e >> 7) * BCAP + lpE] = ((u32)(e & 127) << 16) | (u32)n;
            if (lpN < BCAP) tmpN[(size_t)(n >> 7) * BCAP + lpN] = ((u32)(n & 127) << 16) | (u32)e;
        }
    }
}

// ---------- Pass B: per bucket, compute deg/offs/inv + CSR-ordered adj ----------
__global__ __launch_bounds__(256) void bin_build_kernel(
    const u32* __restrict__ tmpE, const u32* __restrict__ tmpN,
    const int* __restrict__ baseE, const int* __restrict__ baseN,
    int* __restrict__ deg_e, int* __restrict__ offs_e, float* __restrict__ binv, u16* __restrict__ adj_e,
    int* __restrict__ deg_n, int* __restrict__ offs_n, float* __restrict__ dinv, u16* __restrict__ adj_n,
    int nE, int nN, int nbE)
{
    __shared__ u32 buf[4096];
    __shared__ int lcnt[128], lpre[128], lcur[128];
    int b = blockIdx.x;
    const u32* tmp; const int* base; int* deg; int* offs; float* inv; u16* adj; int n, tb;
    if (b < nbE) { tmp=tmpE; base=baseE; deg=deg_e; offs=offs_e; inv=binv; adj=adj_e; n=nE; tb=b; }
    else         { tmp=tmpN; base=baseN; deg=deg_n; offs=offs_n; inv=dinv; adj=adj_n; n=nN; tb=b-nbE; }
    int t = threadIdx.x;
    int g0 = tb << 7;
    int gbase = base[tb];
    int cnt = base[tb + 1] - gbase;
    int avail = cnt < BCAP ? cnt : BCAP;          // drop-guard (never hit for sane data)
    size_t tbase = (size_t)tb * BCAP;
    if (t < 128) lcnt[t] = 0;
    __syncthreads();
    for (int j = t; j < avail; j += 256) atomicAdd(&lcnt[tmp[tbase + j] >> 16], 1);
    __syncthreads();
    if (t < 64) {                                  // 128-wide exclusive prefix, one wave x2
        int a0 = lcnt[2 * t], a1 = lcnt[2 * t + 1];
        int ps = a0 + a1, v = ps;
        for (int o = 1; o < 64; o <<= 1) { int u = __shfl_up(v, o, 64); if (t >= o) v += u; }
        int excl = v - ps;
        lpre[2 * t] = excl; lpre[2 * t + 1] = excl + a0;
    }
    __syncthreads();
    if (t < 128) {
        int id = g0 + t;
        if (id < n) {
            int d = lcnt[t];
            deg[id]  = d;
            offs[id] = gbase + lpre[t];
            inv[id]  = d > 0 ? 1.0f / (float)d : 0.0f;
        }
        lcur[t] = lpre[t];
    }
    __syncthreads();
    if (avail <= 0) return;
    for (int j = t; j < avail; j += 256) {
        u32 v = tmp[tbase + j];
        int pos = atomicAdd(&lcur[v >> 16], 1);
        buf[pos] = v & 0xFFFFu;
    }
    __syncthreads();
    for (int j = t; j < avail; j += 256) adj[gbase + j] = (u16)buf[j];
}

// ---------- XCD-sliced segment gather-sum, SW=32 planes, 8-deep MLP ----------
// src layout: [NP planes][nSrcRows][32] f16. plane = blockIdx & (NP-1); with
// round-robin block->XCD dispatch each plane's 3.2MB working set stays
// L2-resident. One random access = one fully-used 64B line. 8 independent
// line-loads in flight per thread (L2-latency-bound regime).
template<int NP, bool FINAL, int C>
__global__ __launch_bounds__(256) void gather_slice_kernel(
    const f16* __restrict__ src, const u16* __restrict__ adj,
    const int* __restrict__ offs, const int* __restrict__ deg,
    const float* __restrict__ inv, const float* __restrict__ bias,
    void* __restrict__ dstv, int nRows, int nSrcRows)
{
    constexpr int SW = 32;                  // channels per plane
    int t = threadIdx.x;
    int plane = blockIdx.x & (NP - 1);
    int chunk = blockIdx.x / NP;
    int r = chunk * 64 + (t >> 2);          // 64 rows/block, 4 lanes/row
    if (r >= nRows) return;
    int sub = t & 3;
    const f16* sp = src + (size_t)plane * nSrcRows * SW + sub * 8;
    int j = offs[r], e = j + deg[r];
    float a0[8], a1[8], a2[8], a3[8];
    #pragma unroll
    for (int q = 0; q < 8; ++q) { a0[q] = 0.f; a1[q] = 0.f; a2[q] = 0.f; a3[q] = 0.f; }
    for (; j + 8 <= e; j += 8) {            // 8 independent line-loads in flight
        int s0 = adj[j],     s1 = adj[j + 1], s2 = adj[j + 2], s3 = adj[j + 3];
        int s4 = adj[j + 4], s5 = adj[j + 5], s6 = adj[j + 6], s7 = adj[j + 7];
        const half8 v0 = *(const half8*)(sp + (size_t)s0 * SW);
        const half8 v1 = *(const half8*)(sp + (size_t)s1 * SW);
        const half8 v2 = *(const half8*)(sp + (size_t)s2 * SW);
        const half8 v3 = *(const half8*)(sp + (size_t)s3 * SW);
        const half8 v4 = *(const half8*)(sp + (size_t)s4 * SW);
        const half8 v5 = *(const half8*)(sp + (size_t)s5 * SW);
        const half8 v6 = *(const half8*)(sp + (size_t)s6 * SW);
        const half8 v7 = *(const half8*)(sp + (size_t)s7 * SW);
        #pragma unroll
        for (int q = 0; q < 8; ++q) {
            a0[q] += (float)v0[q] + (float)v4[q];
            a1[q] += (float)v1[q] + (float)v5[q];
            a2[q] += (float)v2[q] + (float)v6[q];
            a3[q] += (float)v3[q] + (float)v7[q];
        }
    }
    for (; j + 4 <= e; j += 4) {
        int s0 = adj[j], s1 = adj[j + 1], s2 = adj[j + 2], s3 = adj[j + 3];
        const half8 v0 = *(const half8*)(sp + (size_t)s0 * SW);
        const half8 v1 = *(const half8*)(sp + (size_t)s1 * SW);
        const half8 v2 = *(const half8*)(sp + (size_t)s2 * SW);
        const half8 v3 = *(const half8*)(sp + (size_t)s3 * SW);
        #pragma unroll
        for (int q = 0; q < 8; ++q) {
            a0[q] += (float)v0[q]; a1[q] += (float)v1[q];
            a2[q] += (float)v2[q]; a3[q] += (float)v3[q];
        }
    }
    for (; j < e; ++j) {
        int s0 = adj[j];
        const half8 v0 = *(const half8*)(sp + (size_t)s0 * SW);
        #pragma unroll
        for (int q = 0; q < 8; ++q) a0[q] += (float)v0[q];
    }
    float scv = inv[r];
    float rr[8];
    #pragma unroll
    for (int q = 0; q < 8; ++q) rr[q] = ((a0[q] + a1[q]) + (a2[q] + a3[q])) * scv;
    if constexpr (FINAL) {
        float* dst = (float*)dstv;
        size_t o = (size_t)r * C + plane * SW + sub * 8;
        const float* bp = bias + plane * SW + sub * 8;
        const float4 b0 = *(const float4*)(bp);
        const float4 b1 = *(const float4*)(bp + 4);
        float4 o0, o1;
        o0.x = fmaxf(rr[0] + b0.x, 0.0f); o0.y = fmaxf(rr[1] + b0.y, 0.0f);
        o0.z = fmaxf(rr[2] + b0.z, 0.0f); o0.w = fmaxf(rr[3] + b0.w, 0.0f);
        o1.x = fmaxf(rr[4] + b1.x, 0.0f); o1.y = fmaxf(rr[5] + b1.y, 0.0f);
        o1.z = fmaxf(rr[6] + b1.z, 0.0f); o1.w = fmaxf(rr[7] + b1.w, 0.0f);
        *(float4*)(dst + o)     = o0;
        *(float4*)(dst + o + 4) = o1;
    } else {
        f16* dst = (f16*)dstv;
        half8 ov;
        #pragma unroll
        for (int q = 0; q < 8; ++q) ov[q] = (f16)rr[q];
        *(half8*)(dst + ((size_t)plane * nRows + r) * SW + sub * 8) = ov;
    }
}

// ---------- persistent MFMA split-bf16 GEMM, whole pre-split B in LDS ----------
// C[M,N] = A[M,K] @ B[K,N] (+bias). A f32; B pre-split [K/64][2][N][72] bf16.
// 1024 threads = 16 waves: 8 row-groups x 2 N-halves = 128 rows/tile.
// B staged once, single barrier, then barrier-free loop over row-tiles.
// OUT: 0 = f32 row-major, 1 = f16 plane-major SW=32 (plane = col>>5).
// DOSCAN: blocks 0/1 additionally run the bucket-count scan (64 threads) before
// joining GEMM work - folds the former bkt_scan launch into this one.
__device__ __forceinline__ void split8(const float* __restrict__ p, short8& hi, short8& lo) {
    #pragma unroll
    for (int j = 0; j < 8; ++j) {
        float v = p[j];
        u16 h = f2bf(v);
        hi[j] = (short)h;
        lo[j] = (short)f2bf(v - bf2f(h));
    }
}

template<int K, int N, bool BIAS, int OUT, bool DOSCAN>
__global__ __launch_bounds__(1024) void gemm_mfma_kernel(
    const float* __restrict__ A, const u16* __restrict__ Bsp,
    const float* __restrict__ bias, void* __restrict__ C_, int M,
    const int* __restrict__ curEb, const int* __restrict__ curNb,
    int* __restrict__ baseE, int* __restrict__ baseN, int nbE, int nbN)
{
    constexpr int KP = 72;
    constexpr int NCH = K / 64;
    constexpr int CHUNK = 2 * N * KP;              // u16 per 64-k chunk (hi+lo)
    constexpr int NTW = N / 32;                    // n-tiles per wave
    __shared__ alignas(16) u16 Bbuf[NCH * CHUNK];  // K=256,N=128 -> 144KB
    const int tid = threadIdx.x;
    if constexpr (DOSCAN) {
        if (blockIdx.x < 2 && tid < 64) {
            const int* cur = (blockIdx.x == 0) ? curEb : curNb;
            int* base      = (blockIdx.x == 0) ? baseE : baseN;
            const int nb   = (blockIdx.x == 0) ? nbE : nbN;
            int carry = 0;
            for (int c0 = 0; c0 < nb; c0 += 64) {
                int i = c0 + tid;
                int v = (i < nb) ? cur[i] : 0;
                int orig = v;
                for (int o = 1; o < 64; o <<= 1) { int u = __shfl_up(v, o, 64); if (tid >= o) v += u; }
                if (i < nb) base[i] = carry + v - orig;   // exclusive
                carry += __shfl(v, 63, 64);
            }
            if (tid == 0) base[nb] = carry;
        }
    }
    constexpr int U = NCH * CHUNK / 8;             // 16B units
    for (int u = tid; u < U; u += 1024)
        *(float4*)(&Bbuf[(size_t)u * 8]) = *(const float4*)(Bsp + (size_t)u * 8);
    __syncthreads();
    const int wave = tid >> 6, lane = tid & 63;
    const int mg = wave >> 1, nh = wave & 1;
    const int lr = lane & 15, kq = (lane >> 4) * 8;
    const int nt0 = nh * NTW;
    const int MT = (M + 127) >> 7;
    for (int tile = blockIdx.x; tile < MT; tile += gridDim.x) {
        const int row0 = tile * 128 + mg * 16;
        if (row0 >= M) continue;                   // no barriers in loop -> divergence safe
        f32x4 acc[NTW];
        #pragma unroll
        for (int i = 0; i < NTW; ++i) acc[i] = (f32x4){0.f, 0.f, 0.f, 0.f};
        const float* Ap = A + (size_t)(row0 + lr) * K + kq;
        #pragma unroll
        for (int c = 0; c < NCH; ++c) {
            #pragma unroll
            for (int k0 = 0; k0 < 64; k0 += 32) {
                short8 ah, al;
                split8(Ap + c * 64 + k0, ah, al);
                #pragma unroll
                for (int f = 0; f < NTW; ++f) {
                    const int col = (nt0 + f) * 16 + lr;
                    const int bo = c * CHUNK + col * KP + k0 + kq;
                    const short8 bh = *(const short8*)(&Bbuf[bo]);
                    const short8 bl = *(const short8*)(&Bbuf[bo + N * KP]);
                    acc[f] = __builtin_amdgcn_mfma_f32_16x16x32_bf16(ah, bh, acc[f], 0, 0, 0);
                    acc[f] = __builtin_amdgcn_mfma_f32_16x16x32_bf16(al, bh, acc[f], 0, 0, 0);
                    acc[f] = __builtin_amdgcn_mfma_f32_16x16x32_bf16(ah, bl, acc[f], 0, 0, 0);
                }
            }
        }
        const int orow = row0 + (lane >> 4) * 4;
        #pragma unroll
        for (int f = 0; f < NTW; ++f) {
            const int col = (nt0 + f) * 16 + lr;
            float bv = 0.0f;
            if constexpr (BIAS) bv = bias[col];
            #pragma unroll
            for (int j = 0; j < 4; ++j) {
                float vv = acc[f][j] + bv;
                if constexpr (OUT == 0) {
                    ((float*)C_)[(size_t)(orow + j) * N + col] = vv;
                } else {                           // f16 planes of 32 channels
                    ((f16*)C_)[((size_t)(col >> 5) * M + (orow + j)) * 32 + (col & 31)] = (f16)vv;
                }
            }
        }
    }
}

// ---------- launcher ----------
extern "C" void kernel_launch(void* const* d_in, const int* in_sizes, int n_in,
                              void* d_out, int out_size, void* d_ws, size_t ws_size,
                              hipStream_t stream)
{
    (void)n_in; (void)out_size; (void)ws_size;
    const float* x  = (const float*)d_in[0];
    const int* hidx = (const int*)d_in[1];
    const float* W1 = (const float*)d_in[2];
    const float* b1 = (const float*)d_in[3];
    const float* W2 = (const float*)d_in[4];
    const float* b2 = (const float*)d_in[5];
    const float* Wp = (const float*)d_in[6];
    const float* bp = (const float*)d_in[7];
    float* out = (float*)d_out;

    const int nnz    = in_sizes[1] / 2;    // 800000
    const int nNodes = in_sizes[0] / 256;  // 50000
    const int nEdges = 50000;              // N_EDGES (not derivable from inputs)

    char* w = (char*)d_ws;
    const size_t SEG = 200192;             // >= 50048*4, 256B aligned
    int*   deg_e  = (int*)(w + 0 * SEG);
    int*   deg_n  = (int*)(w + 1 * SEG);
    int*   offs_e = (int*)(w + 2 * SEG);
    int*   offs_n = (int*)(w + 3 * SEG);
    float* binv   = (float*)(w + 4 * SEG);
    float* dinv   = (float*)(w + 5 * SEG);
    int*   curEb  = (int*)(w + 6 * SEG + 256);    // 1024 ints zeroed by wsplit
    int*   curNb  = (int*)(w + 6 * SEG + 2304);   // 391 ints
    int*   baseE  = (int*)(w + 6 * SEG + 4352);   // 392 ints
    int*   baseN  = (int*)(w + 6 * SEG + 6400);   // 392 ints
    char* p = w + 6 * SEG + 8448;
    u16* adj_e = (u16*)p;  p += (size_t)nnz * 2;              // 1.6 MB
    u16* adj_n = (u16*)p;  p += (size_t)nnz * 2;              // 1.6 MB
    f16* h0  = (f16*)p;                                       // 4 planes x 50000 x 32 f16
    f16* m1  = (f16*)(p + (size_t)nNodes * 128 * 2);          // 4 planes x 50000 x 32 f16
    f16* h1w = h0;                                            // reuse: 2 planes x 50000 x 32
    f16* m2  = (f16*)((char*)h0 + (size_t)nNodes * 64 * 2);   // disjoint from h1w
    // pre-split weight images after m1 region
    u16* w1sp = (u16*)(p + 2 * (size_t)nNodes * 128 * 2);     // 4 chunks * 18432 u16
    u16* w2sp = w1sp + 4 * 18432;                             // 2 chunks * 9216 u16
    u16* wpsp = w2sp + 2 * 9216;                              // 1 chunk  * 9216 u16

    const int nbE = (nEdges + 127) >> 7;             // 391
    const int nbN = (nNodes + 127) >> 7;             // 391
    // tmp bucket regions alias m1 (dead until gather1 writes it, after bin_build)
    u32* tmpE = (u32*)m1;
    u32* tmpN = tmpE + (size_t)nbE * BCAP;

    const size_t F1OFF = (size_t)nNodes * 64;        // out: z | f1 | f2 (f32)
    const size_t F2OFF = F1OFF + (size_t)nNodes * 128;

    const int chunksE = (nEdges + 63) / 64;          // 782
    const int chunksN = (nNodes + 63) / 64;          // 782

    // 1: weight split + cursor zero
    wsplit_all_kernel<<<(4*128*72 + 2*64*72 + 1*64*72 + 255) / 256, 256, 0, stream>>>(
        W1, W2, Wp, w1sp, w2sp, wpsp, curEb);
    // 2: bin scatter
    bin_scatter_kernel<<<(nnz + 4095) / 4096, 1024, 0, stream>>>(
        hidx, curEb, curNb, tmpE, tmpN, nnz, nNodes, nEdges);
    // 3: gemm1 (+ folded bucket scan in blocks 0/1)
    gemm_mfma_kernel<256, 128, false, 1, true><<<256, 1024, 0, stream>>>(
        x, w1sp, nullptr, h0, nNodes, curEb, curNb, baseE, baseN, nbE, nbN);
    // 4: CSR build
    bin_build_kernel<<<nbE + nbN, 256, 0, stream>>>(
        tmpE, tmpN, baseE, baseN,
        deg_e, offs_e, binv, adj_e,
        deg_n, offs_n, dinv, adj_n,
        nEdges, nNodes, nbE);
    // 5-6: layer-1 gathers
    gather_slice_kernel<4, false, 128><<<chunksE * 4, 256, 0, stream>>>(
        h0, adj_e, offs_e, deg_e, binv, nullptr, m1, nEdges, nNodes);
    gather_slice_kernel<4, true, 128><<<chunksN * 4, 256, 0, stream>>>(
        m1, adj_n, offs_n, deg_n, dinv, b1, out + F1OFF, nNodes, nEdges);
    // 7: gemm2
    gemm_mfma_kernel<128, 64, false, 1, false><<<391, 1024, 0, stream>>>(
        out + F1OFF, w2sp, nullptr, h1w, nNodes, nullptr, nullptr, nullptr, nullptr, 0, 0);
    // 8-9: layer-2 gathers
    gather_slice_kernel<2, false, 64><<<chunksE * 2, 256, 0, stream>>>(
        h1w, adj_e, offs_e, deg_e, binv, nullptr, m2, nEdges, nNodes);
    gather_slice_kernel<2, true, 64><<<chunksN * 2, 256, 0, stream>>>(
        m2, adj_n, offs_n, deg_n, dinv, b2, out + F2OFF, nNodes, nEdges);
    // 10: projection
    gemm_mfma_kernel<64, 64, true, 0, false><<<391, 1024, 0, stream>>>(
        out + F2OFF, wpsp, bp, out, nNodes, nullptr, nullptr, nullptr, nullptr, 0, 0);
}